// Round 8
// baseline (315.028 us; speedup 1.0000x reference)
//
#include <hip/hip_runtime.h>

#define D        64
#define BINROWS  64
#define SEGCAP   1536       // per final 64-row bin; mean 1280 -> +7 sigma
#define NSB      16         // super-bins
#define NLB      98         // 64-row bins per super-bin
#define SBROWS   (NLB * BINROWS)   // 6272 rows per super-bin
#define NBINS_TOT (NSB * NLB)      // 1568
#define SUPCAP   137216     // per super-bin capacity (mean 125.4k + ~12 sigma)
#define CHUNK    4096
#define PER_TH   (CHUNK / 256)     // 16
#define WG2PER   34         // ceil(SUPCAP / CHUNK)
#define FSTRIDE  68
#define CURSTRIDE 16        // ints per cursor -> own 64 B line

typedef __attribute__((ext_vector_type(8))) short short8;
typedef __attribute__((ext_vector_type(4))) float floatx4;

__device__ __forceinline__ unsigned short f2bf(float f) {
    unsigned u = __float_as_uint(f);
    u += 0x7fffu + ((u >> 16) & 1u);   // RNE
    return (unsigned short)(u >> 16);
}
__device__ __forceinline__ float bf2f(unsigned short u) {
    return __uint_as_float(((unsigned)u) << 16);
}

// ---------------------------------------------------------------------------
// ebs fp32 -> bf16
// ---------------------------------------------------------------------------
__global__ __launch_bounds__(256) void convert_kernel(
    const float* __restrict__ ebs, unsigned short* __restrict__ ebs16, int total4)
{
    int i = blockIdx.x * 256 + threadIdx.x;
    if (i >= total4) return;
    float4 v = ((const float4*)ebs)[i];
    ushort4 o;
    o.x = f2bf(v.x); o.y = f2bf(v.y); o.z = f2bf(v.z); o.w = f2bf(v.w);
    ((ushort4*)ebs16)[i] = o;
}

// ---------------------------------------------------------------------------
// Pack [Ws;Wd] (K=128) into bf16 MFMA B-fragment layout (verified R3).
// ---------------------------------------------------------------------------
__global__ __launch_bounds__(256) void wfrag_kernel(
    const float* __restrict__ W_side, const float* __restrict__ W_dot,
    unsigned short* __restrict__ Wfrag)
{
    int t = blockIdx.x * 256 + threadIdx.x;
    int f = t >> 6;
    int l = t & 63;
    int jt = f >> 2, kt = f & 3;
    int q = l >> 4, nl = l & 15;
    int n = jt * 16 + nl;
#pragma unroll
    for (int j = 0; j < 8; ++j) {
        int k = kt * 32 + q * 8 + j;
        float w = (k < 64) ? W_side[k * 64 + n] : W_dot[(k - 64) * 64 + n];
        Wfrag[(size_t)f * 512 + l * 8 + j] = f2bf(w);
    }
}

// ---------------------------------------------------------------------------
// Pass 1: edges -> 16 super-bins. LDS counting sort of each 4096-edge chunk,
// then per-super-bin COALESCED run write-out (runs ~256 entries = 2 KB).
// super payload: x = (rib<<18)|(m<<17)|col  (rib = row within super-bin, 13b)
//                y = val bits
// ---------------------------------------------------------------------------
__global__ __launch_bounds__(256) void pass1_kernel(
    const int* __restrict__ LI_rows, const int* __restrict__ LI_cols, const float* __restrict__ LI_vals,
    const int* __restrict__ L_rows,  const int* __restrict__ L_cols,  const float* __restrict__ L_vals,
    int* __restrict__ supercur, uint2* __restrict__ superseg, int E)
{
    __shared__ int hist[NSB], offs[NSB], cur[NSB], gbase[NSB];
    __shared__ uint2 sorted[CHUNK];     // 32 KB
    int t = threadIdx.x;
    int c0 = blockIdx.x * CHUNK;
    int twoE = 2 * E;

    if (t < NSB) hist[t] = 0;
    __syncthreads();

    int   keys[PER_TH];
    uint2 pay[PER_TH];
#pragma unroll
    for (int k = 0; k < PER_TH; ++k) {
        int e = c0 + k * 256 + t;
        keys[k] = -1;
        if (e < twoE) {
            int m = (e >= E) ? 1 : 0;
            int r, cl; float v;
            if (m) { r = L_rows[e - E]; cl = L_cols[e - E]; v = L_vals[e - E]; }
            else   { r = LI_rows[e];    cl = LI_cols[e];    v = LI_vals[e]; }
            int sb  = r / SBROWS;
            int rib = r - sb * SBROWS;
            keys[k] = sb;
            pay[k]  = make_uint2(((unsigned)rib << 18) | ((unsigned)m << 17) | (unsigned)cl,
                                 __float_as_uint(v));
            atomicAdd(&hist[sb], 1);
        }
    }
    __syncthreads();

    if (t == 0) {
        int run = 0;
        for (int i = 0; i < NSB; ++i) { offs[i] = run; cur[i] = run; run += hist[i]; }
    }
    __syncthreads();
    if (t < NSB) {
        int c = hist[t];
        gbase[t] = c ? atomicAdd(&supercur[t * CURSTRIDE], c) : 0;
    }
    __syncthreads();

#pragma unroll
    for (int k = 0; k < PER_TH; ++k) {
        if (keys[k] >= 0) {
            int rank = atomicAdd(&cur[keys[k]], 1);
            sorted[rank] = pay[k];
        }
    }
    __syncthreads();

    // coalesced run write-out
    for (int sb = 0; sb < NSB; ++sb) {
        int c = hist[sb], o = offs[sb], gb = gbase[sb];
        size_t base = (size_t)sb * SUPCAP;
        for (int i = t; i < c; i += 256) {
            int pos = gb + i;
            if (pos < SUPCAP) superseg[base + pos] = sorted[o + i];
        }
    }
}

// ---------------------------------------------------------------------------
// Pass 2: super-bin entries -> 98 local 64-row bins. Reads are coalesced;
// LDS counting sort; coalesced run write-out (runs ~42 entries = 336 B).
// final payload: x = (m<<23)|(rowInBin<<17)|col   y = val bits
// ---------------------------------------------------------------------------
__global__ __launch_bounds__(256) void pass2_kernel(
    const uint2* __restrict__ superseg, const int* __restrict__ supercur,
    int* __restrict__ cursor, uint2* __restrict__ seg)
{
    __shared__ int hist[NLB], offs[NLB], cur[NLB], gbase[NLB];
    __shared__ uint2 sorted[CHUNK];     // 32 KB
    int t  = threadIdx.x;
    int sb = blockIdx.x / WG2PER;
    int lw = blockIdx.x % WG2PER;

    int cnt = supercur[sb * CURSTRIDE]; if (cnt > SUPCAP) cnt = SUPCAP;
    int c0  = lw * CHUNK;

    if (t < NLB) hist[t] = 0;
    __syncthreads();

    int   keys[PER_TH];
    uint2 pay[PER_TH];
    const uint2* src = superseg + (size_t)sb * SUPCAP;
#pragma unroll
    for (int k = 0; k < PER_TH; ++k) {
        int i = c0 + k * 256 + t;
        keys[k] = -1;
        if (i < cnt) {
            uint2 en = src[i];
            unsigned rib = en.x >> 18;
            unsigned m   = (en.x >> 17) & 1u;
            unsigned cl  = en.x & 0x1FFFFu;
            int lb = (int)(rib >> 6);
            keys[k] = lb;
            pay[k]  = make_uint2((m << 23) | ((rib & 63u) << 17) | cl, en.y);
            atomicAdd(&hist[lb], 1);
        }
    }
    __syncthreads();

    if (t == 0) {
        int run = 0;
        for (int i = 0; i < NLB; ++i) { offs[i] = run; cur[i] = run; run += hist[i]; }
    }
    __syncthreads();
    if (t < NLB) {
        int c = hist[t];
        gbase[t] = c ? atomicAdd(&cursor[(sb * NLB + t) * CURSTRIDE], c) : 0;
    }
    __syncthreads();

#pragma unroll
    for (int k = 0; k < PER_TH; ++k) {
        if (keys[k] >= 0) {
            int rank = atomicAdd(&cur[keys[k]], 1);
            sorted[rank] = pay[k];
        }
    }
    __syncthreads();

    for (int lb = 0; lb < NLB; ++lb) {
        int c = hist[lb], o = offs[lb], gb = gbase[lb];
        size_t base = (size_t)(sb * NLB + lb) * SEGCAP;
        for (int i = t; i < c; i += 256) {
            int pos = gb + i;
            if (pos < SEGCAP) seg[base + pos] = sorted[o + i];
        }
    }
}

// ---------------------------------------------------------------------------
// Fused v5: per-bin counting sort into LDS, then WAVE-UNIFORM per-key gather
// loops (wave w owns keys [w*32,(w+1)*32), processed in pairs = 2 independent
// load streams; 4 x 16-lane sub-groups slot-parallel per key; shfl_xor
// reduction; plain ds_write per row). MFMA epilogue (verified R5-R7).
// ---------------------------------------------------------------------------
__global__ __launch_bounds__(256) void fused_kernel(
    const uint2* __restrict__ seg, const int* __restrict__ cursorP,
    const unsigned short* __restrict__ ebs16,
    const float* __restrict__ entity,
    const unsigned short* __restrict__ Wfrag,
    float* __restrict__ out, int n)
{
    __shared__ uint2 sseg[SEGCAP];                   // 12 KB sorted entries
    __shared__ float facc[2 * BINROWS * FSTRIDE];    // 34816 B
    __shared__ int hist[128], offs[128], cur[128];

    int t = threadIdx.x;
    int b = blockIdx.x;

    if (t < 128) hist[t] = 0;
    __syncthreads();

    int cnt = cursorP[b * CURSTRIDE]; if (cnt > SEGCAP) cnt = SEGCAP;
    const uint2* sp = seg + (size_t)b * SEGCAP;

    uint2 held[SEGCAP / 256];
    unsigned hmask = 0;
#pragma unroll
    for (int j = 0; j < SEGCAP / 256; ++j) {
        int i = t + j * 256;
        if (i < cnt) {
            held[j] = sp[i];
            hmask |= (1u << j);
            atomicAdd(&hist[(held[j].x >> 17) & 127u], 1);
        }
    }
    __syncthreads();

    // exclusive scan over 128 keys
    if (t < 128) offs[t] = hist[t];
    __syncthreads();
    for (int step = 1; step < 128; step <<= 1) {
        int add = 0;
        if (t < 128 && t >= step) add = offs[t - step];
        __syncthreads();
        if (t < 128) offs[t] += add;
        __syncthreads();
    }
    if (t < 128) {
        int excl = offs[t] - hist[t];
        offs[t] = excl;
        cur[t]  = excl;
    }
    __syncthreads();

#pragma unroll
    for (int j = 0; j < SEGCAP / 256; ++j) {
        if (hmask & (1u << j)) {
            unsigned key = (held[j].x >> 17) & 127u;
            int rank = atomicAdd(&cur[key], 1);
            sseg[rank] = held[j];
        }
    }
    __syncthreads();

    // ---- accumulate: wave-uniform key loops, 2 streams ----
    int w    = t >> 6;
    int lane = t & 63;
    int sub  = lane >> 4;            // slot sub-group 0..3
    int l4   = (lane & 15) << 2;     // dim offset (floats)
    int kbase = w * 32;

    for (int kp = 0; kp < 16; ++kp) {
        int keyA = kbase + kp * 2;
        int keyB = keyA + 1;
        int lenA = hist[keyA], begA = offs[keyA];
        int lenB = hist[keyB], begB = offs[keyB];
        float4 accA = make_float4(0.f, 0.f, 0.f, 0.f);
        float4 accB = make_float4(0.f, 0.f, 0.f, 0.f);
        int mx = max(lenA, lenB);
        for (int s = sub; s < mx; s += 4) {
            if (s < lenA) {
                uint2 en = sseg[begA + s];
                float vv = __uint_as_float(en.y);
                ushort4 x = *(const ushort4*)(ebs16 + (size_t)(en.x & 0x1FFFFu) * D + l4);
                accA.x += vv * bf2f(x.x); accA.y += vv * bf2f(x.y);
                accA.z += vv * bf2f(x.z); accA.w += vv * bf2f(x.w);
            }
            if (s < lenB) {
                uint2 en = sseg[begB + s];
                float vv = __uint_as_float(en.y);
                ushort4 x = *(const ushort4*)(ebs16 + (size_t)(en.x & 0x1FFFFu) * D + l4);
                accB.x += vv * bf2f(x.x); accB.y += vv * bf2f(x.y);
                accB.z += vv * bf2f(x.z); accB.w += vv * bf2f(x.w);
            }
        }
        // reduce across the 4 sub-groups (all lanes end with totals)
        accA.x += __shfl_xor(accA.x, 16); accA.y += __shfl_xor(accA.y, 16);
        accA.z += __shfl_xor(accA.z, 16); accA.w += __shfl_xor(accA.w, 16);
        accA.x += __shfl_xor(accA.x, 32); accA.y += __shfl_xor(accA.y, 32);
        accA.z += __shfl_xor(accA.z, 32); accA.w += __shfl_xor(accA.w, 32);
        accB.x += __shfl_xor(accB.x, 16); accB.y += __shfl_xor(accB.y, 16);
        accB.z += __shfl_xor(accB.z, 16); accB.w += __shfl_xor(accB.w, 16);
        accB.x += __shfl_xor(accB.x, 32); accB.y += __shfl_xor(accB.y, 32);
        accB.z += __shfl_xor(accB.z, 32); accB.w += __shfl_xor(accB.w, 32);

        if (sub == 0) {
            float* dst = facc + ((keyA >> 6) * BINROWS + (keyA & 63)) * FSTRIDE + l4;
            *(float4*)dst = accA;
        }
        if (sub == 1) {
            float* dst = facc + ((keyB >> 6) * BINROWS + (keyB & 63)) * FSTRIDE + l4;
            *(float4*)dst = accB;
        }
    }
    __syncthreads();

    // --- MFMA epilogue: wave w owns bin-rows [w*16, w*16+16) ---
    int l = t & 63;
    int q = l >> 4, mcol = l & 15;
    int rowbase = b * BINROWS + w * 16;
    int growA = rowbase + mcol;
    int binrow = w * 16 + mcol;
    const float* faccLI = facc;
    const float* faccL  = facc + BINROWS * FSTRIDE;

    floatx4 accv[4];
#pragma unroll
    for (int jt = 0; jt < 4; ++jt) accv[jt] = (floatx4){0.f, 0.f, 0.f, 0.f};

#pragma unroll
    for (int kt = 0; kt < 4; ++kt) {
        short8 af;
        if (kt < 2) {
            const float4* ap = (const float4*)(faccLI + binrow * FSTRIDE + kt * 32 + q * 8);
            float4 a0 = ap[0], a1 = ap[1];
            af[0] = (short)f2bf(a0.x); af[1] = (short)f2bf(a0.y);
            af[2] = (short)f2bf(a0.z); af[3] = (short)f2bf(a0.w);
            af[4] = (short)f2bf(a1.x); af[5] = (short)f2bf(a1.y);
            af[6] = (short)f2bf(a1.z); af[7] = (short)f2bf(a1.w);
        } else {
            const float4* lp = (const float4*)(faccL + binrow * FSTRIDE + (kt - 2) * 32 + q * 8);
            float4 l0 = lp[0], l1 = lp[1];
            float4 e0 = make_float4(0.f, 0.f, 0.f, 0.f), e1 = e0;
            if (growA < n) {
                const float4* ep = (const float4*)(entity + (size_t)growA * D + (kt - 2) * 32 + q * 8);
                e0 = ep[0]; e1 = ep[1];
            }
            af[0] = (short)f2bf(l0.x * e0.x); af[1] = (short)f2bf(l0.y * e0.y);
            af[2] = (short)f2bf(l0.z * e0.z); af[3] = (short)f2bf(l0.w * e0.w);
            af[4] = (short)f2bf(l1.x * e1.x); af[5] = (short)f2bf(l1.y * e1.y);
            af[6] = (short)f2bf(l1.z * e1.z); af[7] = (short)f2bf(l1.w * e1.w);
        }
#pragma unroll
        for (int jt = 0; jt < 4; ++jt) {
            const short8 bf = *(const short8*)(Wfrag + (size_t)(jt * 4 + kt) * 512 + (size_t)l * 8);
            accv[jt] = __builtin_amdgcn_mfma_f32_16x16x32_bf16(af, bf, accv[jt], 0, 0, 0);
        }
    }

#pragma unroll
    for (int jt = 0; jt < 4; ++jt) {
#pragma unroll
        for (int r = 0; r < 4; ++r) {
            int grow = rowbase + q * 4 + r;
            if (grow < n) {
                float v = accv[jt][r];
                v = v > 0.f ? v : 0.2f * v;
                out[(size_t)grow * D + jt * 16 + mcol] = v;
            }
        }
    }
}

// ---------------------------------------------------------------------------
// Fallback path (workspace too small): R1 atomic scatter + fp32 epilogue.
// ---------------------------------------------------------------------------
__global__ void scatter_kernel(
    const float* __restrict__ LI_vals, const int* __restrict__ LI_rows, const int* __restrict__ LI_cols,
    const float* __restrict__ L_vals,  const int* __restrict__ L_rows,  const int* __restrict__ L_cols,
    const float* __restrict__ ebs,
    float* __restrict__ accLI, float* __restrict__ accL, int E)
{
    long long t = (long long)blockIdx.x * blockDim.x + threadIdx.x;
    long long e2 = t >> 4;
    if (e2 >= 2LL * E) return;
    int c = ((int)t & 15) << 2;
    const float* vals; const int* rows; const int* cols; float* acc; int e;
    if (e2 < E) { vals = LI_vals; rows = LI_rows; cols = LI_cols; acc = accLI; e = (int)e2; }
    else        { vals = L_vals;  rows = L_rows;  cols = L_cols;  acc = accL;  e = (int)(e2 - E); }
    float v = vals[e]; int r = rows[e]; int cl = cols[e];
    const float4 x = *(const float4*)(ebs + (size_t)cl * D + c);
    float* o = acc + (size_t)r * D + c;
    unsafeAtomicAdd(o + 0, v * x.x);
    unsafeAtomicAdd(o + 1, v * x.y);
    unsafeAtomicAdd(o + 2, v * x.z);
    unsafeAtomicAdd(o + 3, v * x.w);
}

__global__ __launch_bounds__(256) void epilogue_kernel(
    const float* __restrict__ acc, const float* __restrict__ entity,
    const float* __restrict__ W_side, const float* __restrict__ W_dot,
    float* __restrict__ out, int n)
{
    int lane = threadIdx.x & 63;
    int wave = (blockIdx.x << 2) | (threadIdx.x >> 6);
    int row  = (wave << 6) + lane;
    bool valid = row < n;
    const float* accLI = acc;
    const float* accL  = acc + (size_t)n * D;
    float a[D], b[D];
    if (valid) {
        const float4* ap = (const float4*)(accLI  + (size_t)row * D);
        const float4* lp = (const float4*)(accL   + (size_t)row * D);
        const float4* ep = (const float4*)(entity + (size_t)row * D);
#pragma unroll
        for (int qq = 0; qq < 16; ++qq) {
            float4 av = ap[qq]; float4 lv = lp[qq]; float4 ev = ep[qq];
            a[4*qq+0] = av.x; a[4*qq+1] = av.y; a[4*qq+2] = av.z; a[4*qq+3] = av.w;
            b[4*qq+0] = lv.x * ev.x; b[4*qq+1] = lv.y * ev.y;
            b[4*qq+2] = lv.z * ev.z; b[4*qq+3] = lv.w * ev.w;
        }
    } else {
#pragma unroll
        for (int qq = 0; qq < D; ++qq) { a[qq] = 0.f; b[qq] = 0.f; }
    }
    float4* op = (float4*)(out + (size_t)row * D);
#pragma unroll 1
    for (int jc = 0; jc < 16; ++jc) {
        float a0 = 0.f, a1 = 0.f, a2 = 0.f, a3 = 0.f;
#pragma unroll
        for (int k = 0; k < D; ++k) {
            float4 w1 = *(const float4*)(W_side + (k << 6) + (jc << 2));
            float4 w2 = *(const float4*)(W_dot  + (k << 6) + (jc << 2));
            a0 += a[k] * w1.x + b[k] * w2.x;
            a1 += a[k] * w1.y + b[k] * w2.y;
            a2 += a[k] * w1.z + b[k] * w2.z;
            a3 += a[k] * w1.w + b[k] * w2.w;
        }
        float4 r;
        r.x = a0 > 0.f ? a0 : 0.2f * a0;
        r.y = a1 > 0.f ? a1 : 0.2f * a1;
        r.z = a2 > 0.f ? a2 : 0.2f * a2;
        r.w = a3 > 0.f ? a3 : 0.2f * a3;
        if (valid) op[jc] = r;
    }
}

extern "C" void kernel_launch(void* const* d_in, const int* in_sizes, int n_in,
                              void* d_out, int out_size, void* d_ws, size_t ws_size,
                              hipStream_t stream) {
    const float* ebs     = (const float*)d_in[0];
    const float* entity  = (const float*)d_in[1];
    const float* W_side  = (const float*)d_in[2];
    const float* W_dot   = (const float*)d_in[3];
    const float* LI_vals = (const float*)d_in[4];
    const float* L_vals  = (const float*)d_in[5];
    const int*   LI_rows = (const int*)d_in[6];
    const int*   LI_cols = (const int*)d_in[7];
    const int*   L_rows  = (const int*)d_in[8];
    const int*   L_cols  = (const int*)d_in[9];
    float* out = (float*)d_out;

    int E = in_sizes[4];
    int n = in_sizes[0] / D;
    int nbins = (n + BINROWS - 1) / BINROWS;

    size_t scurBytes = (size_t)NSB * CURSTRIDE * sizeof(int);             // 1 KB
    size_t curBytes  = (size_t)NBINS_TOT * CURSTRIDE * sizeof(int);       // 100 KB
    size_t ssegBytes = (size_t)NSB * SUPCAP * sizeof(uint2);              // 17.6 MB
    size_t segBytes  = (size_t)NBINS_TOT * SEGCAP * sizeof(uint2);        // 19.3 MB
    size_t ebsBytes  = (size_t)n * D * sizeof(unsigned short);            // 12.8 MB
    size_t wfBytes   = (size_t)16 * 512 * sizeof(unsigned short);         // 16 KB
    size_t need = scurBytes + curBytes + ssegBytes + segBytes + ebsBytes + wfBytes;

    if (ws_size >= need && n <= NSB * SBROWS && nbins <= NBINS_TOT) {
        char* p = (char*)d_ws;
        int*   supercur = (int*)p;                     p += scurBytes;
        int*   cursor   = (int*)p;                     p += curBytes;
        uint2* superseg = (uint2*)p;                   p += ssegBytes;
        uint2* seg      = (uint2*)p;                   p += segBytes;
        unsigned short* ebs16 = (unsigned short*)p;    p += ebsBytes;
        unsigned short* Wfrag = (unsigned short*)p;

        hipMemsetAsync(d_ws, 0, scurBytes + curBytes, stream);

        int total4 = n * D / 4;
        convert_kernel<<<(total4 + 255) / 256, 256, 0, stream>>>(ebs, ebs16, total4);
        wfrag_kernel<<<4, 256, 0, stream>>>(W_side, W_dot, Wfrag);

        int p1blocks = (2 * E + CHUNK - 1) / CHUNK;
        pass1_kernel<<<p1blocks, 256, 0, stream>>>(
            LI_rows, LI_cols, LI_vals, L_rows, L_cols, L_vals,
            supercur, superseg, E);

        pass2_kernel<<<NSB * WG2PER, 256, 0, stream>>>(
            superseg, supercur, cursor, seg);

        fused_kernel<<<nbins, 256, 0, stream>>>(
            seg, cursor, ebs16, entity, Wfrag, out, n);
    } else {
        size_t accBytes = (size_t)2 * n * D * sizeof(float);
        float* acc   = (float*)d_ws;
        float* accLI = acc;
        float* accL  = accLI + (size_t)n * D;
        hipMemsetAsync(d_ws, 0, accBytes, stream);
        long long totalThreads = 2LL * E * 16;
        int sblocks = (int)((totalThreads + 255) / 256);
        scatter_kernel<<<sblocks, 256, 0, stream>>>(
            LI_vals, LI_rows, LI_cols, L_vals, L_rows, L_cols, ebs, accLI, accL, E);
        int nTiles = (n + 63) / 64;
        epilogue_kernel<<<(nTiles + 3) / 4, 256, 0, stream>>>(
            acc, entity, W_side, W_dot, out, n);
    }
}

// Round 9
// 226.737 us; speedup vs baseline: 1.3894x; 1.3894x over previous
//
#include <hip/hip_runtime.h>

#define D        64
#define BINROWS  64
#define SUBCAP   256        // slots per (shard,bin): mean 160, sigma 12.6 -> +7.6 sigma
#define NSHARD   8
#define NBINS_MAX 1568      // 224*7 (scan layout); n=100k -> 1563 bins used
#define CHUNK    4096
#define PER_TH   (CHUNK / 256)   // 16
#define FSTRIDE  68
#define SSEGCAP  2048       // sorted-entry LDS capacity in fused (8*SUBCAP)
#define CURSTRIDE 16        // ints per cursor -> own 64 B line

typedef __attribute__((ext_vector_type(8))) short short8;
typedef __attribute__((ext_vector_type(4))) float floatx4;

__device__ __forceinline__ unsigned short f2bf(float f) {
    unsigned u = __float_as_uint(f);
    u += 0x7fffu + ((u >> 16) & 1u);   // RNE
    return (unsigned short)(u >> 16);
}
__device__ __forceinline__ float bf2f(unsigned short u) {
    return __uint_as_float(((unsigned)u) << 16);
}

// ---------------------------------------------------------------------------
// ebs fp32 -> bf16
// ---------------------------------------------------------------------------
__global__ __launch_bounds__(256) void convert_kernel(
    const float* __restrict__ ebs, unsigned short* __restrict__ ebs16, int total4)
{
    int i = blockIdx.x * 256 + threadIdx.x;
    if (i >= total4) return;
    float4 v = ((const float4*)ebs)[i];
    ushort4 o;
    o.x = f2bf(v.x); o.y = f2bf(v.y); o.z = f2bf(v.z); o.w = f2bf(v.w);
    ((ushort4*)ebs16)[i] = o;
}

// ---------------------------------------------------------------------------
// Pack [Ws;Wd] (K=128) into bf16 MFMA B-fragment layout (verified R3).
// ---------------------------------------------------------------------------
__global__ __launch_bounds__(256) void wfrag_kernel(
    const float* __restrict__ W_side, const float* __restrict__ W_dot,
    unsigned short* __restrict__ Wfrag)
{
    int t = blockIdx.x * 256 + threadIdx.x;
    int f = t >> 6;
    int l = t & 63;
    int jt = f >> 2, kt = f & 3;
    int q = l >> 4, nl = l & 15;
    int n = jt * 16 + nl;
#pragma unroll
    for (int j = 0; j < 8; ++j) {
        int k = kt * 32 + q * 8 + j;
        float w = (k < 64) ? W_side[k * 64 + n] : W_dot[(k - 64) * 64 + n];
        Wfrag[(size_t)f * 512 + l * 8 + j] = f2bf(w);
    }
}

// ---------------------------------------------------------------------------
// Expand v4: one pass, register-held payloads + full 1568-bin LDS counting
// sort, then SORTED (run-coalesced) write-out to per-(shard,bin) segments.
// Store pattern: consecutive lanes write consecutive addresses within runs
// (~2.6 entries/bin/WG) -> ~2.6x fewer L2 line transactions than random.
// payload.x = (m<<23)|(rowInBin<<17)|col   payload.y = val bits
// ---------------------------------------------------------------------------
__global__ __launch_bounds__(256) void expand_bin_kernel(
    const int* __restrict__ LI_rows, const int* __restrict__ LI_cols, const float* __restrict__ LI_vals,
    const int* __restrict__ L_rows,  const int* __restrict__ L_cols,  const float* __restrict__ L_vals,
    int* __restrict__ cursorP, uint2* __restrict__ seg, int E, int nbins)
{
    __shared__ uint2 sorted[CHUNK];               // 32 KB
    __shared__ unsigned short sbin[CHUNK];        // 8 KB
    __shared__ int hist[NBINS_MAX];               // 6.3 KB
    __shared__ int offs[NBINS_MAX];
    __shared__ int cur[NBINS_MAX];
    __shared__ int gbase[NBINS_MAX];
    __shared__ int tsum[256];

    int t  = threadIdx.x;
    int c0 = blockIdx.x * CHUNK;
    int sh = blockIdx.x & (NSHARD - 1);
    int twoE = 2 * E;
    int chunkcnt = twoE - c0; if (chunkcnt > CHUNK) chunkcnt = CHUNK;

    for (int b = t; b < NBINS_MAX; b += 256) hist[b] = 0;
    __syncthreads();

    unsigned rm[PER_TH];
    uint2    cv[PER_TH];

    // Phase A: read edges into registers, histogram bins
#pragma unroll
    for (int k = 0; k < PER_TH; ++k) {
        int e = c0 + k * 256 + t;
        rm[k] = 0xFFFFFFFFu;
        if (e < twoE) {
            int m = (e >= E) ? 1 : 0;
            int r, cl; float v;
            if (m) { r = L_rows[e - E]; cl = L_cols[e - E]; v = L_vals[e - E]; }
            else   { r = LI_rows[e];    cl = LI_cols[e];    v = LI_vals[e]; }
            rm[k] = (unsigned)r | ((unsigned)m << 17);
            cv[k] = make_uint2((unsigned)cl, __float_as_uint(v));
            atomicAdd(&hist[r >> 6], 1);
        }
    }
    __syncthreads();

    // Phase B: exclusive scan of hist (224 threads x 7 keys + block scan)
    int loc[7]; int tot = 0;
    if (t < 224) {
#pragma unroll
        for (int i = 0; i < 7; ++i) { loc[i] = tot; tot += hist[t * 7 + i]; }
    }
    tsum[t] = (t < 224) ? tot : 0;
    __syncthreads();
    for (int step = 1; step < 256; step <<= 1) {
        int add = (t >= step) ? tsum[t - step] : 0;
        __syncthreads();
        tsum[t] += add;
        __syncthreads();
    }
    int tbase = tsum[t] - ((t < 224) ? tot : 0);
    if (t < 224) {
#pragma unroll
        for (int i = 0; i < 7; ++i) {
            int key = t * 7 + i;
            int o = tbase + loc[i];
            offs[key] = o;
            cur[key]  = o;
        }
    }
    __syncthreads();

    // Phase B2: reserve global runs in this WG's shard (padded cursors)
    for (int b = t; b < nbins; b += 256) {
        int c = hist[b];
        gbase[b] = c ? atomicAdd(&cursorP[(sh * NBINS_MAX + b) * CURSTRIDE], c) : 0;
    }

    // Phase C: scatter payloads into the LDS-sorted array
#pragma unroll
    for (int k = 0; k < PER_TH; ++k) {
        unsigned g = rm[k];
        if (g == 0xFFFFFFFFu) continue;
        int r   = (int)(g & 0x1FFFFu);
        int m   = (int)((g >> 17) & 1u);
        int bin = r >> 6;
        int rank = atomicAdd(&cur[bin], 1);
        sorted[rank] = make_uint2(((unsigned)m << 23) | ((unsigned)(r & 63) << 17) | cv[k].x, cv[k].y);
        sbin[rank]   = (unsigned short)bin;
    }
    __syncthreads();

    // Phase D: coalesced run write-out (consecutive entries -> consecutive addrs)
    for (int i = t; i < chunkcnt; i += 256) {
        int bin = sbin[i];
        int pos = gbase[bin] + (i - offs[bin]);
        if (pos < SUBCAP)
            seg[((size_t)(sh * NBINS_MAX) + bin) * SUBCAP + pos] = sorted[i];
    }
}

// ---------------------------------------------------------------------------
// Fused v6: R7 structure (union'd LDS, 4 WG/CU) with BRANCHLESS gather loop:
// idx = beg + min(s, len-1), vv/col masked -> zero exec divergence, 8
// unconditional global loads per s-step that batch under one vmcnt.
// ---------------------------------------------------------------------------
__global__ __launch_bounds__(256) void fused_kernel(
    const uint2* __restrict__ seg, const int* __restrict__ cursorP,
    const unsigned short* __restrict__ ebs16,
    const float* __restrict__ entity,
    const unsigned short* __restrict__ Wfrag,
    float* __restrict__ out, int n)
{
    __shared__ __align__(16) char shmem[2 * BINROWS * FSTRIDE * 4];  // 34816 B
    __shared__ int hist[128];
    __shared__ int offs[128];
    __shared__ int cur[128];
    uint2* sseg = (uint2*)shmem;          // sorted entries (<= 2048 * 8 B = 16 KB)
    float* facc = (float*)shmem;          // reused after accumulate barrier

    int t = threadIdx.x;
    int b = blockIdx.x;

    if (t < 128) hist[t] = 0;
    __syncthreads();

    // Load per-shard counts + this thread's entries (<=1/shard, SUBCAP==256)
    int clen[NSHARD];
    uint2 held[NSHARD];
    unsigned hmask = 0;
#pragma unroll
    for (int sh = 0; sh < NSHARD; ++sh) {
        int c = cursorP[(sh * NBINS_MAX + b) * CURSTRIDE];
        clen[sh] = c < SUBCAP ? c : SUBCAP;
        if (t < clen[sh]) {
            held[sh] = seg[((size_t)(sh * NBINS_MAX) + b) * SUBCAP + t];
            hmask |= (1u << sh);
            atomicAdd(&hist[(held[sh].x >> 17) & 127u], 1);
        }
    }
    __syncthreads();

    // exclusive scan over 128 keys
    if (t < 128) offs[t] = hist[t];
    __syncthreads();
    for (int step = 1; step < 128; step <<= 1) {
        int add = 0;
        if (t < 128 && t >= step) add = offs[t - step];
        __syncthreads();
        if (t < 128) offs[t] += add;
        __syncthreads();
    }
    if (t < 128) {
        int excl = offs[t] - hist[t];
        offs[t] = excl;
        cur[t]  = excl;
    }
    __syncthreads();

#pragma unroll
    for (int sh = 0; sh < NSHARD; ++sh) {
        if (hmask & (1u << sh)) {
            unsigned key = (held[sh].x >> 17) & 127u;
            int rank = atomicAdd(&cur[key], 1);
            sseg[rank] = held[sh];
        }
    }
    __syncthreads();

    // Accumulate: group g (16 lanes) owns keys [g*8, g*8+8); branchless.
    int g  = t >> 4;
    int l4 = (t & 15) << 2;
    int beg[8], len[8], lenm1[8];
    int maxlen = 0;
#pragma unroll
    for (int kk = 0; kk < 8; ++kk) {
        int key = g * 8 + kk;
        beg[kk]   = offs[key];
        len[kk]   = hist[key];
        lenm1[kk] = len[kk] > 0 ? len[kk] - 1 : 0;
        maxlen = max(maxlen, len[kk]);
    }
    floatx4 a8[8];
#pragma unroll
    for (int kk = 0; kk < 8; ++kk) a8[kk] = (floatx4){0.f, 0.f, 0.f, 0.f};

    for (int s = 0; s < maxlen; ++s) {
#pragma unroll
        for (int kk = 0; kk < 8; ++kk) {
            bool sel = s < len[kk];
            int idx  = beg[kk] + min(s, lenm1[kk]);
            uint2 en = sseg[idx];                       // LDS broadcast
            unsigned enx = sel ? en.x : 0u;             // masks col (OOB safety)
            float vv = sel ? __uint_as_float(en.y) : 0.f;
            ushort4 x = *(const ushort4*)(ebs16 + (size_t)(enx & 0x1FFFFu) * D + l4);
            a8[kk][0] += vv * bf2f(x.x);
            a8[kk][1] += vv * bf2f(x.y);
            a8[kk][2] += vv * bf2f(x.z);
            a8[kk][3] += vv * bf2f(x.w);
        }
    }
    __syncthreads();   // all sseg reads done before facc overwrites the union

#pragma unroll
    for (int kk = 0; kk < 8; ++kk) {
        int key = g * 8 + kk;
        float* dst = facc + ((key >> 6) * BINROWS + (key & 63)) * FSTRIDE + l4;
        *(float4*)dst = make_float4(a8[kk][0], a8[kk][1], a8[kk][2], a8[kk][3]);
    }
    __syncthreads();

    // --- MFMA epilogue (verified R5-R8): wave w owns bin-rows [w*16,+16) ---
    int w = t >> 6;
    int l = t & 63;
    int q = l >> 4, mcol = l & 15;
    int rowbase = b * BINROWS + w * 16;
    int growA = rowbase + mcol;
    int binrow = w * 16 + mcol;
    const float* faccLI = facc;
    const float* faccL  = facc + BINROWS * FSTRIDE;

    floatx4 accv[4];
#pragma unroll
    for (int jt = 0; jt < 4; ++jt) accv[jt] = (floatx4){0.f, 0.f, 0.f, 0.f};

#pragma unroll
    for (int kt = 0; kt < 4; ++kt) {
        short8 af;
        if (kt < 2) {
            const float4* ap = (const float4*)(faccLI + binrow * FSTRIDE + kt * 32 + q * 8);
            float4 a0 = ap[0], a1 = ap[1];
            af[0] = (short)f2bf(a0.x); af[1] = (short)f2bf(a0.y);
            af[2] = (short)f2bf(a0.z); af[3] = (short)f2bf(a0.w);
            af[4] = (short)f2bf(a1.x); af[5] = (short)f2bf(a1.y);
            af[6] = (short)f2bf(a1.z); af[7] = (short)f2bf(a1.w);
        } else {
            const float4* lp = (const float4*)(faccL + binrow * FSTRIDE + (kt - 2) * 32 + q * 8);
            float4 l0 = lp[0], l1 = lp[1];
            float4 e0 = make_float4(0.f, 0.f, 0.f, 0.f), e1 = e0;
            if (growA < n) {
                const float4* ep = (const float4*)(entity + (size_t)growA * D + (kt - 2) * 32 + q * 8);
                e0 = ep[0]; e1 = ep[1];
            }
            af[0] = (short)f2bf(l0.x * e0.x); af[1] = (short)f2bf(l0.y * e0.y);
            af[2] = (short)f2bf(l0.z * e0.z); af[3] = (short)f2bf(l0.w * e0.w);
            af[4] = (short)f2bf(l1.x * e1.x); af[5] = (short)f2bf(l1.y * e1.y);
            af[6] = (short)f2bf(l1.z * e1.z); af[7] = (short)f2bf(l1.w * e1.w);
        }
#pragma unroll
        for (int jt = 0; jt < 4; ++jt) {
            const short8 bf = *(const short8*)(Wfrag + (size_t)(jt * 4 + kt) * 512 + (size_t)l * 8);
            accv[jt] = __builtin_amdgcn_mfma_f32_16x16x32_bf16(af, bf, accv[jt], 0, 0, 0);
        }
    }

#pragma unroll
    for (int jt = 0; jt < 4; ++jt) {
#pragma unroll
        for (int r = 0; r < 4; ++r) {
            int grow = rowbase + q * 4 + r;
            if (grow < n) {
                float v = accv[jt][r];
                v = v > 0.f ? v : 0.2f * v;
                out[(size_t)grow * D + jt * 16 + mcol] = v;
            }
        }
    }
}

// ---------------------------------------------------------------------------
// Fallback path (workspace too small): R1 atomic scatter + fp32 epilogue.
// ---------------------------------------------------------------------------
__global__ void scatter_kernel(
    const float* __restrict__ LI_vals, const int* __restrict__ LI_rows, const int* __restrict__ LI_cols,
    const float* __restrict__ L_vals,  const int* __restrict__ L_rows,  const int* __restrict__ L_cols,
    const float* __restrict__ ebs,
    float* __restrict__ accLI, float* __restrict__ accL, int E)
{
    long long t = (long long)blockIdx.x * blockDim.x + threadIdx.x;
    long long e2 = t >> 4;
    if (e2 >= 2LL * E) return;
    int c = ((int)t & 15) << 2;
    const float* vals; const int* rows; const int* cols; float* acc; int e;
    if (e2 < E) { vals = LI_vals; rows = LI_rows; cols = LI_cols; acc = accLI; e = (int)e2; }
    else        { vals = L_vals;  rows = L_rows;  cols = L_cols;  acc = accL;  e = (int)(e2 - E); }
    float v = vals[e]; int r = rows[e]; int cl = cols[e];
    const float4 x = *(const float4*)(ebs + (size_t)cl * D + c);
    float* o = acc + (size_t)r * D + c;
    unsafeAtomicAdd(o + 0, v * x.x);
    unsafeAtomicAdd(o + 1, v * x.y);
    unsafeAtomicAdd(o + 2, v * x.z);
    unsafeAtomicAdd(o + 3, v * x.w);
}

__global__ __launch_bounds__(256) void epilogue_kernel(
    const float* __restrict__ acc, const float* __restrict__ entity,
    const float* __restrict__ W_side, const float* __restrict__ W_dot,
    float* __restrict__ out, int n)
{
    int lane = threadIdx.x & 63;
    int wave = (blockIdx.x << 2) | (threadIdx.x >> 6);
    int row  = (wave << 6) + lane;
    bool valid = row < n;
    const float* accLI = acc;
    const float* accL  = acc + (size_t)n * D;
    float a[D], b[D];
    if (valid) {
        const float4* ap = (const float4*)(accLI  + (size_t)row * D);
        const float4* lp = (const float4*)(accL   + (size_t)row * D);
        const float4* ep = (const float4*)(entity + (size_t)row * D);
#pragma unroll
        for (int qq = 0; qq < 16; ++qq) {
            float4 av = ap[qq]; float4 lv = lp[qq]; float4 ev = ep[qq];
            a[4*qq+0] = av.x; a[4*qq+1] = av.y; a[4*qq+2] = av.z; a[4*qq+3] = av.w;
            b[4*qq+0] = lv.x * ev.x; b[4*qq+1] = lv.y * ev.y;
            b[4*qq+2] = lv.z * ev.z; b[4*qq+3] = lv.w * ev.w;
        }
    } else {
#pragma unroll
        for (int qq = 0; qq < D; ++qq) { a[qq] = 0.f; b[qq] = 0.f; }
    }
    float4* op = (float4*)(out + (size_t)row * D);
#pragma unroll 1
    for (int jc = 0; jc < 16; ++jc) {
        float a0 = 0.f, a1 = 0.f, a2 = 0.f, a3 = 0.f;
#pragma unroll
        for (int k = 0; k < D; ++k) {
            float4 w1 = *(const float4*)(W_side + (k << 6) + (jc << 2));
            float4 w2 = *(const float4*)(W_dot  + (k << 6) + (jc << 2));
            a0 += a[k] * w1.x + b[k] * w2.x;
            a1 += a[k] * w1.y + b[k] * w2.y;
            a2 += a[k] * w1.z + b[k] * w2.z;
            a3 += a[k] * w1.w + b[k] * w2.w;
        }
        float4 r;
        r.x = a0 > 0.f ? a0 : 0.2f * a0;
        r.y = a1 > 0.f ? a1 : 0.2f * a1;
        r.z = a2 > 0.f ? a2 : 0.2f * a2;
        r.w = a3 > 0.f ? a3 : 0.2f * a3;
        if (valid) op[jc] = r;
    }
}

extern "C" void kernel_launch(void* const* d_in, const int* in_sizes, int n_in,
                              void* d_out, int out_size, void* d_ws, size_t ws_size,
                              hipStream_t stream) {
    const float* ebs     = (const float*)d_in[0];
    const float* entity  = (const float*)d_in[1];
    const float* W_side  = (const float*)d_in[2];
    const float* W_dot   = (const float*)d_in[3];
    const float* LI_vals = (const float*)d_in[4];
    const float* L_vals  = (const float*)d_in[5];
    const int*   LI_rows = (const int*)d_in[6];
    const int*   LI_cols = (const int*)d_in[7];
    const int*   L_rows  = (const int*)d_in[8];
    const int*   L_cols  = (const int*)d_in[9];
    float* out = (float*)d_out;

    int E = in_sizes[4];
    int n = in_sizes[0] / D;
    int nbins = (n + BINROWS - 1) / BINROWS;

    size_t curBytes = (size_t)NSHARD * NBINS_MAX * CURSTRIDE * sizeof(int);   // 0.80 MB
    size_t segBytes = (size_t)NSHARD * NBINS_MAX * SUBCAP * sizeof(uint2);    // 25.7 MB
    size_t ebsBytes = (size_t)n * D * sizeof(unsigned short);                 // 12.8 MB
    size_t wfBytes  = (size_t)16 * 512 * sizeof(unsigned short);              // 16 KB
    size_t need = curBytes + segBytes + ebsBytes + wfBytes;

    if (ws_size >= need && nbins <= NBINS_MAX && n <= 131072) {
        int*            cursorP = (int*)d_ws;
        uint2*          seg     = (uint2*)((char*)d_ws + curBytes);
        unsigned short* ebs16   = (unsigned short*)((char*)d_ws + curBytes + segBytes);
        unsigned short* Wfrag   = (unsigned short*)((char*)d_ws + curBytes + segBytes + ebsBytes);

        hipMemsetAsync(cursorP, 0, curBytes, stream);

        int total4 = n * D / 4;
        convert_kernel<<<(total4 + 255) / 256, 256, 0, stream>>>(ebs, ebs16, total4);
        wfrag_kernel<<<4, 256, 0, stream>>>(W_side, W_dot, Wfrag);

        int xblocks = (2 * E + CHUNK - 1) / CHUNK;
        expand_bin_kernel<<<xblocks, 256, 0, stream>>>(
            LI_rows, LI_cols, LI_vals, L_rows, L_cols, L_vals,
            cursorP, seg, E, nbins);

        fused_kernel<<<nbins, 256, 0, stream>>>(
            seg, cursorP, ebs16, entity, Wfrag, out, n);
    } else {
        size_t accBytes = (size_t)2 * n * D * sizeof(float);
        float* acc   = (float*)d_ws;
        float* accLI = acc;
        float* accL  = accLI + (size_t)n * D;
        hipMemsetAsync(d_ws, 0, accBytes, stream);
        long long totalThreads = 2LL * E * 16;
        int sblocks = (int)((totalThreads + 255) / 256);
        scatter_kernel<<<sblocks, 256, 0, stream>>>(
            LI_vals, LI_rows, LI_cols, L_vals, L_rows, L_cols, ebs, accLI, accL, E);
        int nTiles = (n + 63) / 64;
        epilogue_kernel<<<(nTiles + 3) / 4, 256, 0, stream>>>(
            acc, entity, W_side, W_dot, out, n);
    }
}